// Round 1
// baseline (1166.396 us; speedup 1.0000x reference)
//
#include <hip/hip_runtime.h>
#include <hip/hip_fp16.h>
#include <stdint.h>

#define DIM 384
#define WIN 64
#define HEADS 12
#define HD 32
#define NWIN 4096

typedef _Float16 f16;
typedef unsigned int u32;
typedef _Float16 half8 __attribute__((ext_vector_type(8)));
typedef _Float16 half4 __attribute__((ext_vector_type(4)));
typedef float floatx4 __attribute__((ext_vector_type(4)));

#define AS1 __attribute__((address_space(1)))
#define AS3 __attribute__((address_space(3)))

__device__ __forceinline__ void gl_lds16(const void* g, void* l) {
    __builtin_amdgcn_global_load_lds((const AS1 u32*)g, (AS3 u32*)l, 16, 0, 0);
}

// ---------------- fp32 -> fp16 convert (vectorized x4) ----------------
__global__ void cvt_kernel(const float* __restrict__ in, f16* __restrict__ out, long n4) {
    long i = (long)blockIdx.x * blockDim.x + threadIdx.x;
    const long stride = (long)gridDim.x * blockDim.x;
    for (; i < n4; i += stride) {
        float4 v = ((const float4*)in)[i];
        half4 h;
        h[0] = (f16)v.x; h[1] = (f16)v.y; h[2] = (f16)v.z; h[3] = (f16)v.w;
        ((half4*)out)[i] = h;
    }
}

// ---------------- GEMM: C[M][N] = A[M][K=384] * Bw[N][K=384]^T ----------------
// MODE 0: N=1152 qkv epilogue (scatter q/k row-major, v interleaved)
// MODE 1: N=384 proj epilogue (+bias, fp32 out)
template<int MODE>
__global__ void gemm_kernel(const f16* __restrict__ A, const f16* __restrict__ Bw,
                            f16* __restrict__ q_arr, f16* __restrict__ k_arr,
                            f16* __restrict__ v_int,
                            float* __restrict__ outp, const float* __restrict__ proj_b)
{
    // [buf][A/B][kc][row][kk] : per buffer A=8KB, B=8KB; total 32KB
    __shared__ __align__(16) f16 lds[2][2][4][128][8];
    const int tid  = threadIdx.x;
    const int wave = tid >> 6, lane = tid & 63;
    const int g = lane >> 4, c = lane & 15;
    const int wm = wave >> 1, wn = wave & 1;
    const int col0 = blockIdx.x * 128;
    const int row0 = blockIdx.y * 128;

    floatx4 acc[4][4] = {};

    auto stage = [&](int s, int bufi) {
        const int k0 = s * 32;
#pragma unroll
        for (int r = 0; r < 4; ++r) {
            const int u = wave + r * 4;       // 0..15
            const int isB = u >> 3;
            const int uu = u & 7;
            const int kc = uu >> 1, m0 = (uu & 1) * 64;
            const f16* src = (isB ? Bw + (size_t)(col0 + m0 + lane) * DIM
                                  : A  + (size_t)(row0 + m0 + lane) * DIM)
                             + k0 + kc * 8;
            gl_lds16(src, &lds[bufi][isB][kc][m0][0]);
        }
    };

    int buf = 0;
    stage(0, 0);
#pragma unroll 2
    for (int s = 0; s < 12; ++s) {
        __syncthreads();
        if (s + 1 < 12) stage(s + 1, buf ^ 1);
        half8 af[4], bf[4];
#pragma unroll
        for (int i = 0; i < 4; ++i) {
            af[i] = *(const half8*)&lds[buf][0][g][wm * 64 + i * 16 + c][0];
            bf[i] = *(const half8*)&lds[buf][1][g][wn * 64 + i * 16 + c][0];
        }
#pragma unroll
        for (int mi = 0; mi < 4; ++mi)
#pragma unroll
            for (int ni = 0; ni < 4; ++ni)
                acc[mi][ni] = __builtin_amdgcn_mfma_f32_16x16x32_f16(
                    af[mi], bf[ni], acc[mi][ni], 0, 0, 0);
        buf ^= 1;
    }

    if (MODE == 0) {
        const int which = col0 / DIM;          // 0=q 1=k 2=v (blocks never straddle)
        const int dbase = col0 - which * DIM;
        const int b0 = blockIdx.y * 2 + wm;    // window index within chunk
        if (which < 2) {
            f16* dst = which ? k_arr : q_arr;
            const float sc = which ? 1.0f : 0.17677669529663687f; // 32^-0.5 folded into q
#pragma unroll
            for (int ni = 0; ni < 4; ++ni) {
                const int d = dbase + wn * 64 + ni * 16 + c;
                const int h = d >> 5, e = d & 31;
                f16* base = dst + (size_t)(b0 * HEADS + h) * (WIN * HD) + e;
#pragma unroll
                for (int mi = 0; mi < 4; ++mi)
#pragma unroll
                    for (int j = 0; j < 4; ++j) {
                        const int n = mi * 16 + g * 4 + j;
                        base[(size_t)n * HD] = (f16)(acc[mi][ni][j] * sc);
                    }
            }
        } else {
            // v interleaved: v_int[b,h][m>>3][e][m&7]  (8B packed stores)
#pragma unroll
            for (int ni = 0; ni < 4; ++ni) {
                const int d = dbase + wn * 64 + ni * 16 + c;
                const int h = d >> 5, e = d & 31;
                f16* vb = v_int + (size_t)(b0 * HEADS + h) * (WIN * HD);
#pragma unroll
                for (int mi = 0; mi < 4; ++mi) {
                    const int n0 = mi * 16 + g * 4;
                    half4 pk;
#pragma unroll
                    for (int j = 0; j < 4; ++j) pk[j] = (f16)acc[mi][ni][j];
                    *(half4*)(vb + (n0 >> 3) * 256 + e * 8 + (n0 & 7)) = pk;
                }
            }
        }
    } else {
#pragma unroll
        for (int ni = 0; ni < 4; ++ni) {
            const int d = col0 + wn * 64 + ni * 16 + c;
            const float pb = proj_b[d];
#pragma unroll
            for (int mi = 0; mi < 4; ++mi)
#pragma unroll
                for (int j = 0; j < 4; ++j) {
                    const size_t trow = (size_t)row0 + wm * 64 + mi * 16 + g * 4 + j;
                    outp[trow * DIM + d] = acc[mi][ni][j] + pb;
                }
        }
    }
}

// ---------------- attention: one block per (window, head) ----------------
__global__ void attn_kernel(const f16* __restrict__ q_arr, const f16* __restrict__ k_arr,
                            const f16* __restrict__ v_int,
                            const float* __restrict__ bias_table,
                            f16* __restrict__ attn_out)
{
    const int bid = blockIdx.x;
    const int bw = bid / HEADS, h = bid % HEADS;
    const f16* q = q_arr + (size_t)bid * (WIN * HD);
    const f16* k = k_arr + (size_t)bid * (WIN * HD);
    const f16* v = v_int + (size_t)bid * (WIN * HD);

    const int tid = threadIdx.x;
    const int w = tid >> 6, lane = tid & 63;
    const int g = lane >> 4, c = lane & 15;

    __shared__ float bias_lds[2 * WIN - 1];
    __shared__ __align__(16) f16 p_lds[8][64][8];   // P in A-frag-interleaved layout

    for (int i = tid; i < 2 * WIN - 1; i += 256)
        bias_lds[i] = bias_table[(size_t)i * HEADS + h];
    __syncthreads();

    // S = Q K^T : wave w owns rows 16w..16w+15, all 64 cols
    half8 qa = *(const half8*)(q + (16 * w + c) * HD + g * 8);
    floatx4 s[4];
#pragma unroll
    for (int t = 0; t < 4; ++t) {
        half8 kb = *(const half8*)(k + (16 * t + c) * HD + g * 8);
        floatx4 z = {};
        s[t] = __builtin_amdgcn_mfma_f32_16x16x32_f16(qa, kb, z, 0, 0, 0);
    }

    // bias + row softmax (row = 16w + g*4 + j; 64 cols live in 16-lane group x 4 tiles)
    float pr[4][4];
#pragma unroll
    for (int j = 0; j < 4; ++j) {
        const int n = 16 * w + g * 4 + j;
        float mx = -1e30f;
#pragma unroll
        for (int t = 0; t < 4; ++t) {
            const int m = 16 * t + c;
            pr[j][t] = s[t][j] + bias_lds[n - m + 63];
            mx = fmaxf(mx, pr[j][t]);
        }
        mx = fmaxf(mx, __shfl_xor(mx, 1));
        mx = fmaxf(mx, __shfl_xor(mx, 2));
        mx = fmaxf(mx, __shfl_xor(mx, 4));
        mx = fmaxf(mx, __shfl_xor(mx, 8));
        float sum = 0.f;
#pragma unroll
        for (int t = 0; t < 4; ++t) { pr[j][t] = __expf(pr[j][t] - mx); sum += pr[j][t]; }
        sum += __shfl_xor(sum, 1);
        sum += __shfl_xor(sum, 2);
        sum += __shfl_xor(sum, 4);
        sum += __shfl_xor(sum, 8);
        const float r = 1.0f / sum;
#pragma unroll
        for (int t = 0; t < 4; ++t) {
            const int m = 16 * t + c;
            p_lds[m >> 3][n][m & 7] = (f16)(pr[j][t] * r);
        }
    }
    __syncthreads();

    // O = P V : rows 16w.., cols 0..31 (K=64 split in 2 mfma)
    half8 pa0 = *(const half8*)&p_lds[g][16 * w + c][0];
    half8 pa1 = *(const half8*)&p_lds[4 + g][16 * w + c][0];
    floatx4 o[2];
#pragma unroll
    for (int t = 0; t < 2; ++t) {
        half8 vb0 = *(const half8*)(v + g * 256 + (16 * t + c) * 8);
        half8 vb1 = *(const half8*)(v + (4 + g) * 256 + (16 * t + c) * 8);
        floatx4 z = {};
        o[t] = __builtin_amdgcn_mfma_f32_16x16x32_f16(pa0, vb0, z, 0, 0, 0);
        o[t] = __builtin_amdgcn_mfma_f32_16x16x32_f16(pa1, vb1, o[t], 0, 0, 0);
    }
#pragma unroll
    for (int t = 0; t < 2; ++t)
#pragma unroll
        for (int j = 0; j < 4; ++j) {
            const int n = 16 * w + g * 4 + j;
            attn_out[((size_t)bw * WIN + n) * DIM + h * HD + 16 * t + c] = (f16)o[t][j];
        }
}

extern "C" void kernel_launch(void* const* d_in, const int* in_sizes, int n_in,
                              void* d_out, int out_size, void* d_ws, size_t ws_size,
                              hipStream_t stream) {
    const float* x          = (const float*)d_in[0];
    const float* qkv_w      = (const float*)d_in[1];
    const float* proj_w     = (const float*)d_in[2];
    const float* proj_b     = (const float*)d_in[3];
    const float* bias_table = (const float*)d_in[4];
    float* out = (float*)d_out;
    (void)in_sizes; (void)n_in; (void)out_size;

    uintptr_t p = (uintptr_t)d_ws;
    auto carve = [&](size_t bytes) -> void* {
        uintptr_t q = p; p += (bytes + 255) & ~(size_t)255; return (void*)q;
    };
    f16* w16_qkv  = (f16*)carve((size_t)3 * DIM * DIM * 2);
    f16* w16_proj = (f16*)carve((size_t)DIM * DIM * 2);
    const size_t fixed = p - (uintptr_t)d_ws;

    // chunk windows so ws fits: per-window = x16 + q + k + v + attn_out = 5*49152 B
    int CB = NWIN;
    while (CB > 2 && fixed + (size_t)CB * 245760 + 4096 > ws_size) CB >>= 1;

    f16* x16 = (f16*)carve((size_t)CB * WIN * DIM * 2);
    f16* qa  = (f16*)carve((size_t)CB * HEADS * WIN * HD * 2);
    f16* ka  = (f16*)carve((size_t)CB * HEADS * WIN * HD * 2);
    f16* vi  = (f16*)carve((size_t)CB * HEADS * WIN * HD * 2);
    f16* ao  = (f16*)carve((size_t)CB * WIN * DIM * 2);

    cvt_kernel<<<dim3(256), dim3(256), 0, stream>>>(qkv_w, w16_qkv, (long)(3 * DIM * DIM / 4));
    cvt_kernel<<<dim3(64),  dim3(256), 0, stream>>>(proj_w, w16_proj, (long)(DIM * DIM / 4));

    for (int c0 = 0; c0 < NWIN; c0 += CB) {
        const float* xc = x + (size_t)c0 * WIN * DIM;
        const long n4 = (long)CB * WIN * DIM / 4;
        cvt_kernel<<<dim3(2048), dim3(256), 0, stream>>>(xc, x16, n4);

        dim3 g1(3 * DIM / 128, CB * WIN / 128);
        gemm_kernel<0><<<g1, dim3(256), 0, stream>>>(x16, w16_qkv, qa, ka, vi, nullptr, nullptr);

        attn_kernel<<<dim3(CB * HEADS), dim3(256), 0, stream>>>(qa, ka, vi, bias_table, ao);

        dim3 g3(DIM / 128, CB * WIN / 128);
        gemm_kernel<1><<<g3, dim3(256), 0, stream>>>(ao, w16_proj, nullptr, nullptr, nullptr,
                                                     out + (size_t)c0 * WIN * DIM, proj_b);
    }
}

// Round 2
// 1059.302 us; speedup vs baseline: 1.1011x; 1.1011x over previous
//
#include <hip/hip_runtime.h>
#include <stdint.h>

#define DIM 384
#define WIN 64
#define HEADS 12
#define HD 32
#define NWIN 4096

typedef _Float16 f16;
typedef unsigned int u32;
typedef _Float16 half8 __attribute__((ext_vector_type(8)));
typedef _Float16 half4 __attribute__((ext_vector_type(4)));
typedef float floatx4 __attribute__((ext_vector_type(4)));

#define AS1 __attribute__((address_space(1)))
#define AS3 __attribute__((address_space(3)))

__device__ __forceinline__ void gl_lds16(const void* g, void* l) {
    __builtin_amdgcn_global_load_lds((const AS1 u32*)g, (AS3 u32*)l, 16, 0, 0);
}

// ---------------- fp32 -> fp16 convert (weights only) ----------------
__global__ void cvt_kernel(const float* __restrict__ in, f16* __restrict__ out, long n4) {
    long i = (long)blockIdx.x * blockDim.x + threadIdx.x;
    const long stride = (long)gridDim.x * blockDim.x;
    for (; i < n4; i += stride) {
        float4 v = ((const float4*)in)[i];
        half4 h;
        h[0] = (f16)v.x; h[1] = (f16)v.y; h[2] = (f16)v.z; h[3] = (f16)v.w;
        ((half4*)out)[i] = h;
    }
}

// ---------------- QKV GEMM: C[M][1152] = A32[M][384](fp32, cvt in-kernel) * Bw[1152][384]^T
// 1D grid, XCD-swizzled, col-block innermost (9 col-blocks share an A-tile on one XCD L2).
__global__ void qkv_kernel(const float* __restrict__ A32, const f16* __restrict__ Bw,
                           f16* __restrict__ q_arr, f16* __restrict__ k_arr,
                           f16* __restrict__ v_int, int nwg)
{
    __shared__ __align__(16) f16 xa[2][4][128][8];   // A tile dbuf, 16 KB
    __shared__ __align__(16) f16 bst[2][4][128][8];  // B tile dbuf, 16 KB

    int lin = blockIdx.x;
    int nlin = lin;
    if ((nwg & 7) == 0) nlin = (lin & 7) * (nwg >> 3) + (lin >> 3);
    const int colb = nlin % 9, rowb = nlin / 9;
    const int col0 = colb * 128, row0 = rowb * 128;

    const int tid = threadIdx.x;
    const int wave = tid >> 6, lane = tid & 63;
    const int g = lane >> 4, c = lane & 15;
    const int wm = wave >> 1, wn = wave & 1;

    floatx4 acc[4][4] = {};
    float4 rA[4];

    auto loadA = [&](int s) {
        const int k0 = s * 32;
#pragma unroll
        for (int r = 0; r < 4; ++r) {
            const int i = r * 256 + tid;
            const int row = i >> 3, kq = i & 7;
            rA[r] = *(const float4*)(A32 + (size_t)(row0 + row) * DIM + k0 + kq * 4);
        }
    };
    auto writeA = [&](int nb) {
#pragma unroll
        for (int r = 0; r < 4; ++r) {
            const int i = r * 256 + tid;
            const int row = i >> 3, kq = i & 7;
            half4 h;
            h[0] = (f16)rA[r].x; h[1] = (f16)rA[r].y; h[2] = (f16)rA[r].z; h[3] = (f16)rA[r].w;
            *(half4*)&xa[nb][kq >> 1][row][(kq & 1) * 4] = h;
        }
    };
    auto stageB = [&](int s, int nb) {
        const int k0 = s * 32;
#pragma unroll
        for (int r = 0; r < 2; ++r) {
            const int m = wave + r * 4;          // 0..7 : 8 wave-calls of 64x16B
            const int sl = m * 64 + lane;        // 0..511
            const int kc = sl >> 7, u = sl & 127;
            gl_lds16(Bw + (size_t)(col0 + u) * DIM + k0 + kc * 8,
                     (f16*)&bst[nb][0][0][0] + m * 512);
        }
    };

    loadA(0); stageB(0, 0); writeA(0);
    int buf = 0;
    for (int s = 0; s < 12; ++s) {
        __syncthreads();
        if (s < 11) { loadA(s + 1); stageB(s + 1, buf ^ 1); }
        half8 af[4], bf[4];
#pragma unroll
        for (int i = 0; i < 4; ++i) {
            af[i] = *(const half8*)&xa[buf][g][wm * 64 + i * 16 + c][0];
            bf[i] = *(const half8*)&bst[buf][g][wn * 64 + i * 16 + c][0];
        }
#pragma unroll
        for (int mi = 0; mi < 4; ++mi)
#pragma unroll
            for (int ni = 0; ni < 4; ++ni)
                acc[mi][ni] = __builtin_amdgcn_mfma_f32_16x16x32_f16(
                    af[mi], bf[ni], acc[mi][ni], 0, 0, 0);
        if (s < 11) writeA(buf ^ 1);
        buf ^= 1;
    }

    // epilogue: scatter q/k row-major per (b,h), v interleaved for attn B-frags
    const int which = colb / 3;            // 0=q 1=k 2=v
    const int dbase = col0 - which * DIM;
    const int b0 = rowb * 2 + wm;          // window index within chunk
    if (which < 2) {
        f16* dst = which ? k_arr : q_arr;
        const float sc = which ? 1.0f : 0.17677669529663687f;  // 32^-0.5 folded into q
#pragma unroll
        for (int ni = 0; ni < 4; ++ni) {
            const int d = dbase + wn * 64 + ni * 16 + c;
            const int h = d >> 5, e = d & 31;
            f16* base = dst + (size_t)(b0 * HEADS + h) * (WIN * HD) + e;
#pragma unroll
            for (int mi = 0; mi < 4; ++mi)
#pragma unroll
                for (int j = 0; j < 4; ++j) {
                    const int n = mi * 16 + g * 4 + j;
                    base[(size_t)n * HD] = (f16)(acc[mi][ni][j] * sc);
                }
        }
    } else {
#pragma unroll
        for (int ni = 0; ni < 4; ++ni) {
            const int d = dbase + wn * 64 + ni * 16 + c;
            const int h = d >> 5, e = d & 31;
            f16* vb = v_int + (size_t)(b0 * HEADS + h) * (WIN * HD);
#pragma unroll
            for (int mi = 0; mi < 4; ++mi) {
                const int n0 = mi * 16 + g * 4;
                half4 pk;
#pragma unroll
                for (int j = 0; j < 4; ++j) pk[j] = (f16)acc[mi][ni][j];
                *(half4*)(vb + (n0 >> 3) * 256 + e * 8 + (n0 & 7)) = pk;
            }
        }
    }
}

// ---------------- proj GEMM: out[M][384] = A[M][384](f16) * Bw[384][384]^T + bias (fp32 out)
__global__ void proj_kernel(const f16* __restrict__ A, const f16* __restrict__ Bw,
                            float* __restrict__ outp, const float* __restrict__ proj_b,
                            int nwg)
{
    __shared__ __align__(16) f16 lds[2][2][4][128][8];

    int lin = blockIdx.x;
    int nlin = lin;
    if ((nwg & 7) == 0) nlin = (lin & 7) * (nwg >> 3) + (lin >> 3);
    const int colb = nlin % 3, rowb = nlin / 3;
    const int col0 = colb * 128, row0 = rowb * 128;

    const int tid = threadIdx.x;
    const int wave = tid >> 6, lane = tid & 63;
    const int g = lane >> 4, c = lane & 15;
    const int wm = wave >> 1, wn = wave & 1;

    floatx4 acc[4][4] = {};

    auto stage = [&](int s, int bufi) {
        const int k0 = s * 32;
#pragma unroll
        for (int r = 0; r < 4; ++r) {
            const int u = wave + r * 4;       // 0..15
            const int isB = u >> 3;
            const int uu = u & 7;
            const int kc = uu >> 1, m0 = (uu & 1) * 64;
            const f16* src = (isB ? Bw + (size_t)(col0 + m0 + lane) * DIM
                                  : A  + (size_t)(row0 + m0 + lane) * DIM)
                             + k0 + kc * 8;
            gl_lds16(src, &lds[bufi][isB][kc][m0][0]);
        }
    };

    int buf = 0;
    stage(0, 0);
    for (int s = 0; s < 12; ++s) {
        __syncthreads();
        if (s + 1 < 12) stage(s + 1, buf ^ 1);
        half8 af[4], bf[4];
#pragma unroll
        for (int i = 0; i < 4; ++i) {
            af[i] = *(const half8*)&lds[buf][0][g][wm * 64 + i * 16 + c][0];
            bf[i] = *(const half8*)&lds[buf][1][g][wn * 64 + i * 16 + c][0];
        }
#pragma unroll
        for (int mi = 0; mi < 4; ++mi)
#pragma unroll
            for (int ni = 0; ni < 4; ++ni)
                acc[mi][ni] = __builtin_amdgcn_mfma_f32_16x16x32_f16(
                    af[mi], bf[ni], acc[mi][ni], 0, 0, 0);
        buf ^= 1;
    }

#pragma unroll
    for (int ni = 0; ni < 4; ++ni) {
        const int d = col0 + wn * 64 + ni * 16 + c;
        const float pb = proj_b[d];
#pragma unroll
        for (int mi = 0; mi < 4; ++mi)
#pragma unroll
            for (int j = 0; j < 4; ++j) {
                const size_t trow = (size_t)row0 + wm * 64 + mi * 16 + g * 4 + j;
                outp[trow * DIM + d] = acc[mi][ni][j] + pb;
            }
    }
}

// ---------------- attention: one block per (window, head) ----------------
__global__ void attn_kernel(const f16* __restrict__ q_arr, const f16* __restrict__ k_arr,
                            const f16* __restrict__ v_int,
                            const float* __restrict__ bias_table,
                            f16* __restrict__ attn_out)
{
    const int bid = blockIdx.x;
    const int bw = bid / HEADS, h = bid % HEADS;
    const f16* q = q_arr + (size_t)bid * (WIN * HD);
    const f16* k = k_arr + (size_t)bid * (WIN * HD);
    const f16* v = v_int + (size_t)bid * (WIN * HD);

    const int tid = threadIdx.x;
    const int w = tid >> 6, lane = tid & 63;
    const int g = lane >> 4, c = lane & 15;

    __shared__ float bias_lds[2 * WIN - 1];
    __shared__ __align__(16) f16 p_lds[8][64][8];   // P in A-frag-interleaved layout

    for (int i = tid; i < 2 * WIN - 1; i += 256)
        bias_lds[i] = bias_table[(size_t)i * HEADS + h];
    __syncthreads();

    // S = Q K^T : wave w owns rows 16w..16w+15, all 64 cols
    half8 qa = *(const half8*)(q + (16 * w + c) * HD + g * 8);
    floatx4 s[4];
#pragma unroll
    for (int t = 0; t < 4; ++t) {
        half8 kb = *(const half8*)(k + (16 * t + c) * HD + g * 8);
        floatx4 z = {};
        s[t] = __builtin_amdgcn_mfma_f32_16x16x32_f16(qa, kb, z, 0, 0, 0);
    }

    // bias + row softmax (row = 16w + g*4 + j; cols split over 16-lane group x 4 tiles)
    float pr[4][4];
#pragma unroll
    for (int j = 0; j < 4; ++j) {
        const int n = 16 * w + g * 4 + j;
        float mx = -1e30f;
#pragma unroll
        for (int t = 0; t < 4; ++t) {
            const int m = 16 * t + c;
            pr[j][t] = s[t][j] + bias_lds[n - m + 63];
            mx = fmaxf(mx, pr[j][t]);
        }
        mx = fmaxf(mx, __shfl_xor(mx, 1));
        mx = fmaxf(mx, __shfl_xor(mx, 2));
        mx = fmaxf(mx, __shfl_xor(mx, 4));
        mx = fmaxf(mx, __shfl_xor(mx, 8));
        float sum = 0.f;
#pragma unroll
        for (int t = 0; t < 4; ++t) { pr[j][t] = __expf(pr[j][t] - mx); sum += pr[j][t]; }
        sum += __shfl_xor(sum, 1);
        sum += __shfl_xor(sum, 2);
        sum += __shfl_xor(sum, 4);
        sum += __shfl_xor(sum, 8);
        const float r = 1.0f / sum;
#pragma unroll
        for (int t = 0; t < 4; ++t) {
            const int m = 16 * t + c;
            p_lds[m >> 3][n][m & 7] = (f16)(pr[j][t] * r);
        }
    }
    __syncthreads();

    // O = P V : rows 16w.., cols 0..31 (K=64 split in 2 mfma)
    half8 pa0 = *(const half8*)&p_lds[g][16 * w + c][0];
    half8 pa1 = *(const half8*)&p_lds[4 + g][16 * w + c][0];
    floatx4 o[2];
#pragma unroll
    for (int t = 0; t < 2; ++t) {
        half8 vb0 = *(const half8*)(v + g * 256 + (16 * t + c) * 8);
        half8 vb1 = *(const half8*)(v + (4 + g) * 256 + (16 * t + c) * 8);
        floatx4 z = {};
        o[t] = __builtin_amdgcn_mfma_f32_16x16x32_f16(pa0, vb0, z, 0, 0, 0);
        o[t] = __builtin_amdgcn_mfma_f32_16x16x32_f16(pa1, vb1, o[t], 0, 0, 0);
    }
#pragma unroll
    for (int t = 0; t < 2; ++t)
#pragma unroll
        for (int j = 0; j < 4; ++j) {
            const int n = 16 * w + g * 4 + j;
            attn_out[((size_t)bw * WIN + n) * DIM + h * HD + 16 * t + c] = (f16)o[t][j];
        }
}

extern "C" void kernel_launch(void* const* d_in, const int* in_sizes, int n_in,
                              void* d_out, int out_size, void* d_ws, size_t ws_size,
                              hipStream_t stream) {
    const float* x          = (const float*)d_in[0];
    const float* qkv_w      = (const float*)d_in[1];
    const float* proj_w     = (const float*)d_in[2];
    const float* proj_b     = (const float*)d_in[3];
    const float* bias_table = (const float*)d_in[4];
    float* out = (float*)d_out;
    (void)in_sizes; (void)n_in; (void)out_size;

    uintptr_t p = (uintptr_t)d_ws;
    auto carve = [&](size_t bytes) -> void* {
        uintptr_t q = p; p += (bytes + 255) & ~(size_t)255; return (void*)q;
    };
    f16* w16_qkv  = (f16*)carve((size_t)3 * DIM * DIM * 2);
    f16* w16_proj = (f16*)carve((size_t)DIM * DIM * 2);
    const size_t fixed = p - (uintptr_t)d_ws;

    // per-window ws: q + k + v + ao = 4 * 49152 B
    int CB = NWIN;
    while (CB > 16 && fixed + (size_t)CB * 196608 + 4096 > ws_size) CB >>= 1;

    f16* qa = (f16*)carve((size_t)CB * HEADS * WIN * HD * 2);
    f16* ka = (f16*)carve((size_t)CB * HEADS * WIN * HD * 2);
    f16* vi = (f16*)carve((size_t)CB * HEADS * WIN * HD * 2);
    f16* ao = (f16*)carve((size_t)CB * WIN * DIM * 2);

    cvt_kernel<<<dim3(256), dim3(256), 0, stream>>>(qkv_w, w16_qkv, (long)(3 * DIM * DIM / 4));
    cvt_kernel<<<dim3(64),  dim3(256), 0, stream>>>(proj_w, w16_proj, (long)(DIM * DIM / 4));

    for (int c0 = 0; c0 < NWIN; c0 += CB) {
        const float* xc = x + (size_t)c0 * WIN * DIM;

        const int nwg1 = (CB * WIN / 128) * 9;
        qkv_kernel<<<dim3(nwg1), dim3(256), 0, stream>>>(xc, w16_qkv, qa, ka, vi, nwg1);

        attn_kernel<<<dim3(CB * HEADS), dim3(256), 0, stream>>>(qa, ka, vi, bias_table, ao);

        const int nwg2 = (CB * WIN / 128) * 3;
        proj_kernel<<<dim3(nwg2), dim3(256), 0, stream>>>(ao, w16_proj,
                                                          out + (size_t)c0 * WIN * DIM, proj_b, nwg2);
    }
}